// Round 2
// baseline (379.012 us; speedup 1.0000x reference)
//
#include <hip/hip_runtime.h>

#define NBINS 256
#define HWPIX (512 * 512)      // pixels per channel
#define NCHAN (64 * 3)         // N*C channels
#define HIST_BPC 8             // blocks per channel, histogram pass
#define APPLY_BPC 16           // blocks per channel, apply pass
#define NCOPY 32               // replicated LDS tables: copy c lives in bank c

// Zero the per-channel histograms in workspace (harness poisons ws with 0xAA).
__global__ void zero_hist(int* __restrict__ hist) {
    hist[blockIdx.x * blockDim.x + threadIdx.x] = 0;
}

// Pass 1: per-channel 256-bin histogram.
// Conflict-free layout: lh[bin*32 + copy], lane l uses copy l>>1, so every
// LDS atomic from lane l hits bank (l>>1): exactly 2 lanes/bank (free, m136).
__global__ __launch_bounds__(256) void hist_kernel(const float* __restrict__ x,
                                                   int* __restrict__ hist) {
    __shared__ int lh[NBINS * NCOPY];   // 32 KiB
    const int chan = blockIdx.x / HIST_BPC;
    const int blk  = blockIdx.x % HIST_BPC;
    const int tid  = threadIdx.x;
    const int cp   = (tid & 63) >> 1;   // bank-private copy id

    for (int i = tid; i < NBINS * NCOPY; i += 256) lh[i] = 0;
    __syncthreads();

    const float4* base = (const float4*)x + (size_t)chan * (HWPIX / 4);
    const int vecPerBlock = HWPIX / 4 / HIST_BPC;  // 8192
    const int start = blk * vecPerBlock;

    for (int i = tid; i < vecPerBlock; i += 256) {
        float4 v = base[start + i];
        atomicAdd(&lh[(((int)fminf(fmaxf(v.x, 0.f), 255.f)) << 5) + cp], 1);
        atomicAdd(&lh[(((int)fminf(fmaxf(v.y, 0.f), 255.f)) << 5) + cp], 1);
        atomicAdd(&lh[(((int)fminf(fmaxf(v.z, 0.f), 255.f)) << 5) + cp], 1);
        atomicAdd(&lh[(((int)fminf(fmaxf(v.w, 0.f), 255.f)) << 5) + cp], 1);
    }
    __syncthreads();

    // Reduce 32 copies of bin `tid`. Rotate copy index so lane t reads bank
    // (t+k)%32 at step k: 2-way conflicts only.
    int s = 0;
    #pragma unroll
    for (int k = 0; k < NCOPY; ++k) {
        int c = (tid + k) & (NCOPY - 1);
        s += lh[(tid << 5) + c];
    }
    if (s) atomicAdd(&hist[chan * NBINS + tid], s);
}

// Pass 2: each block recomputes its channel's LUT from the global histogram
// (exact int arithmetic == the fp32 reference, all values < 2^24), then
// applies it via a 32-way replicated LDS LUT (conflict-free gather).
__global__ __launch_bounds__(256) void apply_kernel(const float* __restrict__ x,
                                                    float* __restrict__ out,
                                                    const int* __restrict__ hist) {
    __shared__ int scan[NBINS];
    __shared__ float slut[NBINS * NCOPY];   // 32 KiB
    __shared__ int s_last_idx;
    __shared__ int s_last;

    const int chan = blockIdx.x / APPLY_BPC;
    const int blk  = blockIdx.x % APPLY_BPC;
    const int tid  = threadIdx.x;
    const int cp   = (tid & 63) >> 1;

    const int h = hist[chan * NBINS + tid];
    scan[tid] = h;
    if (tid == 0) s_last_idx = 0;
    __syncthreads();
    if (h > 0) atomicMax(&s_last_idx, tid);

    // inclusive scan over 256 bins (Hillis-Steele)
    for (int off = 1; off < NBINS; off <<= 1) {
        __syncthreads();
        int t = (tid >= off) ? scan[tid - off] : 0;
        __syncthreads();
        scan[tid] += t;
    }
    __syncthreads();
    if (tid == s_last_idx) s_last = h;  // count of last nonzero bin
    __syncthreads();

    const int total = scan[NBINS - 1];
    const int step  = (total - s_last) / 255;  // floor, nonneg

    float lutv;
    if (step == 0) {
        lutv = (float)tid;                      // identity mapping
    } else if (tid == 0) {
        lutv = 0.f;                             // shifted-in leading zero
    } else {
        int l = (scan[tid - 1] + (step >> 1)) / step;
        lutv = (float)(l < 255 ? l : 255);
    }
    // broadcast LUT into 32 bank-private copies (rotated: 2-way conflicts only)
    #pragma unroll
    for (int k = 0; k < NCOPY; ++k) {
        int c = (tid + k) & (NCOPY - 1);
        slut[(tid << 5) + c] = lutv;
    }
    __syncthreads();

    const float4* bx = (const float4*)x + (size_t)chan * (HWPIX / 4);
    float4*       bo = (float4*)out + (size_t)chan * (HWPIX / 4);
    const int vecPerBlock = HWPIX / 4 / APPLY_BPC;  // 4096
    const int start = blk * vecPerBlock;

    for (int i = tid; i < vecPerBlock; i += 256) {
        float4 v = bx[start + i];
        float4 o;
        o.x = slut[(((int)fminf(fmaxf(v.x, 0.f), 255.f)) << 5) + cp];
        o.y = slut[(((int)fminf(fmaxf(v.y, 0.f), 255.f)) << 5) + cp];
        o.z = slut[(((int)fminf(fmaxf(v.z, 0.f), 255.f)) << 5) + cp];
        o.w = slut[(((int)fminf(fmaxf(v.w, 0.f), 255.f)) << 5) + cp];
        bo[start + i] = o;
    }
}

extern "C" void kernel_launch(void* const* d_in, const int* in_sizes, int n_in,
                              void* d_out, int out_size, void* d_ws, size_t ws_size,
                              hipStream_t stream) {
    const float* x = (const float*)d_in[0];
    // d_in[1] is `magnitude` — unused by the reference.
    float* out = (float*)d_out;
    int* hist = (int*)d_ws;  // NCHAN * NBINS int32 = 192 KiB

    zero_hist<<<NCHAN, NBINS, 0, stream>>>(hist);
    hist_kernel<<<NCHAN * HIST_BPC, 256, 0, stream>>>(x, hist);
    apply_kernel<<<NCHAN * APPLY_BPC, 256, 0, stream>>>(x, out, hist);
}

// Round 4
// 376.642 us; speedup vs baseline: 1.0063x; 1.0063x over previous
//
#include <hip/hip_runtime.h>

#define NBINS 256
#define NCHAN 192                         // 64*3 channels
#define HIST_BPC 8                        // blocks per channel, pass 1
#define APPLY_BPC 16                      // blocks per channel, pass 2
#define TPB 256
#define VEC_PER_CHAN (512 * 512 / 4)      // 65536 float4 (== packed uints) per channel
#define NCOPY 32                          // bank-private LDS table replication

// Pass 1: read x once; clamp->u8; write packed uchar4 image to ws; build
// per-channel histogram in bank-private replicated LDS (lane l -> copy l>>1,
// so every DS op hits bank l>>1: 2 lanes/bank = free). Plain-store per-block
// partial histograms (no zeroing, no global atomics).
__global__ __launch_bounds__(TPB) void hist_pack(const float* __restrict__ x,
                                                 unsigned* __restrict__ packed,
                                                 int* __restrict__ partials) {
    __shared__ int lh[NBINS * NCOPY];     // 32 KiB
    const int chan = blockIdx.x / HIST_BPC;
    const int blk  = blockIdx.x % HIST_BPC;
    const int tid  = threadIdx.x;
    const int cp   = (tid & 63) >> 1;

    for (int i = tid; i < NBINS * NCOPY; i += TPB) lh[i] = 0;
    __syncthreads();

    const int vecPerBlock = VEC_PER_CHAN / HIST_BPC;  // 8192
    const size_t base = (size_t)chan * VEC_PER_CHAN + blk * vecPerBlock;
    const float4* bx = (const float4*)x + base;
    unsigned* bp = packed + base;

    for (int i = tid; i < vecPerBlock; i += TPB) {
        float4 v = bx[i];
        int a = (int)fminf(fmaxf(v.x, 0.f), 255.f);
        int b = (int)fminf(fmaxf(v.y, 0.f), 255.f);
        int c = (int)fminf(fmaxf(v.z, 0.f), 255.f);
        int d = (int)fminf(fmaxf(v.w, 0.f), 255.f);
        bp[i] = (unsigned)(a | (b << 8) | (c << 16) | (d << 24));
        atomicAdd(&lh[(a << 5) + cp], 1);
        atomicAdd(&lh[(b << 5) + cp], 1);
        atomicAdd(&lh[(c << 5) + cp], 1);
        atomicAdd(&lh[(d << 5) + cp], 1);
    }
    __syncthreads();

    // reduce the 32 copies of bin `tid` (rotated -> 2-way conflicts only)
    int s = 0;
    #pragma unroll
    for (int k = 0; k < NCOPY; ++k) s += lh[(tid << 5) + ((tid + k) & 31)];
    partials[(chan * HIST_BPC + blk) * NBINS + tid] = s;
}

// Pass 2: sum the 8 partials -> channel histogram; exact-int scan -> LUT
// (identical to the fp32 reference: all intermediates < 2^24); replicate LUT
// into bank-private LDS copies; gather from the packed u8 image; write out.
__global__ __launch_bounds__(TPB) void apply_kernel(const unsigned* __restrict__ packed,
                                                    float* __restrict__ out,
                                                    const int* __restrict__ partials) {
    __shared__ int scan[NBINS];
    __shared__ float slut[NBINS * NCOPY]; // 32 KiB
    __shared__ int s_last_idx, s_last;

    const int chan = blockIdx.x / APPLY_BPC;
    const int blk  = blockIdx.x % APPLY_BPC;
    const int tid  = threadIdx.x;
    const int cp   = (tid & 63) >> 1;

    int h = 0;
    #pragma unroll
    for (int b = 0; b < HIST_BPC; ++b)
        h += partials[(chan * HIST_BPC + b) * NBINS + tid];
    scan[tid] = h;
    if (tid == 0) s_last_idx = 0;
    __syncthreads();
    if (h > 0) atomicMax(&s_last_idx, tid);

    for (int off = 1; off < NBINS; off <<= 1) {   // inclusive Hillis-Steele scan
        __syncthreads();
        int t = (tid >= off) ? scan[tid - off] : 0;
        __syncthreads();
        scan[tid] += t;
    }
    __syncthreads();
    if (tid == s_last_idx) s_last = h;            // count of last nonzero bin
    __syncthreads();

    const int total = scan[NBINS - 1];
    const int step  = (total - s_last) / 255;     // floor, nonneg

    float lutv;
    if (step == 0)      lutv = (float)tid;        // identity
    else if (tid == 0)  lutv = 0.f;               // shifted-in leading zero
    else {
        int l = (scan[tid - 1] + (step >> 1)) / step;
        lutv = (float)(l < 255 ? l : 255);
    }
    #pragma unroll
    for (int k = 0; k < NCOPY; ++k) slut[(tid << 5) + ((tid + k) & 31)] = lutv;
    __syncthreads();

    const int vecPerBlock = VEC_PER_CHAN / APPLY_BPC;  // 4096
    const size_t base = (size_t)chan * VEC_PER_CHAN + blk * vecPerBlock;
    const unsigned* bp = packed + base;
    float4* bo = (float4*)out + base;

    for (int i = tid; i < vecPerBlock; i += TPB) {
        unsigned p = bp[i];
        float4 o;
        o.x = slut[(int)((p & 255u) << 5) + cp];
        o.y = slut[(int)(((p >> 8) & 255u) << 5) + cp];
        o.z = slut[(int)(((p >> 16) & 255u) << 5) + cp];
        o.w = slut[(int)((p >> 24) << 5) + cp];
        bo[i] = o;
    }
}

extern "C" void kernel_launch(void* const* d_in, const int* in_sizes, int n_in,
                              void* d_out, int out_size, void* d_ws, size_t ws_size,
                              hipStream_t stream) {
    const float* x = (const float*)d_in[0];
    // d_in[1] is `magnitude` — unused by the reference.
    float* out = (float*)d_out;

    // ws layout: [packed u8 image: 192*65536 uints = 48 MiB][partials: 1.5 MiB]
    unsigned* packed = (unsigned*)d_ws;
    int* partials = (int*)d_ws + (size_t)NCHAN * VEC_PER_CHAN;

    hist_pack<<<NCHAN * HIST_BPC, TPB, 0, stream>>>(x, packed, partials);
    apply_kernel<<<NCHAN * APPLY_BPC, TPB, 0, stream>>>(packed, out, partials);
}